// Round 1
// baseline (473.261 us; speedup 1.0000x reference)
//
#include <hip/hip_runtime.h>

typedef float  f32x4 __attribute__((ext_vector_type(4)));
typedef short  s16x8 __attribute__((ext_vector_type(8)));

__device__ __forceinline__ short f2bf(float f) {
  unsigned u = __builtin_bit_cast(unsigned, f);
  u += 0x7FFFu + ((u >> 16) & 1u);   // round-to-nearest-even
  return (short)(u >> 16);
}

// ---------------------------------------------------------------------------
// Kernel 1: Y^T build.  Yt[c][k] = bf16( sum_d x[k][d] * W[d][c] )
// 5 segments, zero-padded to Kpad (multiple of 32).
// Offsets (elements): v2v 0 (32*6016), v2e 192512, e2e 385024 (32*12000),
//                     e2f 769024, f2f 1153024; total 1409024 (2.82 MB).
// ---------------------------------------------------------------------------
__global__ __launch_bounds__(256) void build_yt(
    const float* __restrict__ xv, const float* __restrict__ xe,
    const float* __restrict__ xf,
    const float* __restrict__ Wv2v, const float* __restrict__ Wv2e,
    const float* __restrict__ We2e, const float* __restrict__ We2f,
    const float* __restrict__ Wf2f, short* __restrict__ Yt)
{
  int bid = blockIdx.x;
  const float* x; const float* W; int K, Kpad; size_t yoff;
  if (bid < 24)       { x=xv; W=Wv2v; K=6000;  Kpad=6016;  yoff=0;       }
  else if (bid < 48)  { x=xv; W=Wv2e; K=6000;  Kpad=6016;  yoff=192512;  bid-=24; }
  else if (bid < 95)  { x=xe; W=We2e; K=12000; Kpad=12000; yoff=385024;  bid-=48; }
  else if (bid < 142) { x=xe; W=We2f; K=12000; Kpad=12000; yoff=769024;  bid-=95; }
  else                { x=xf; W=Wf2f; K=8000;  Kpad=8000;  yoff=1153024; bid-=142; }

  __shared__ float Wl[32][32];
  int tid = threadIdx.x;
  #pragma unroll
  for (int i = 0; i < 4; ++i) {
    int e = tid + i * 256;
    Wl[e >> 5][e & 31] = W[e];
  }
  __syncthreads();

  int row = bid * 256 + tid;
  if (row >= Kpad) return;

  float acc[32];
  #pragma unroll
  for (int c = 0; c < 32; ++c) acc[c] = 0.f;

  if (row < K) {
    const float* xp = x + (size_t)row * 32;
    float xr[32];
    #pragma unroll
    for (int i = 0; i < 8; ++i) {
      f32x4 v = *(const f32x4*)(xp + i * 4);
      xr[i*4+0] = v.x; xr[i*4+1] = v.y; xr[i*4+2] = v.z; xr[i*4+3] = v.w;
    }
    #pragma unroll
    for (int d = 0; d < 32; ++d) {
      float xd = xr[d];
      #pragma unroll
      for (int c = 0; c < 32; ++c) acc[c] += xd * Wl[d][c];
    }
  }
  #pragma unroll
  for (int c = 0; c < 32; ++c)
    Yt[yoff + (size_t)c * Kpad + row] = f2bf(acc[c]);
}

// ---------------------------------------------------------------------------
// Kernel 2: skinny GEMM.  Each block: one 16-row x 32-col output tile,
// 4 waves split the (concatenated) K range, LDS reduce, plain store.
// A-frag (16x32 of G, fp32->bf16): lane l = row (l&15), k = 8*(l>>4)+i,
// loaded straight from global (G has zero reuse).
// B-frag from Y^T: lane l = col (l&15), same k chunk -> 16B contiguous.
// ---------------------------------------------------------------------------
__device__ __forceinline__ void run_seg(
    const float* __restrict__ G, const short* __restrict__ Yt,
    int K, int Kpad, int row0, int s_lo, int s_hi, int lane,
    f32x4& acc0, f32x4& acc1)
{
  if (s_lo >= s_hi) return;
  int r = lane & 15, g = lane >> 4;
  const float* gp = G + (size_t)(row0 + r) * K;
  const short* b0 = Yt + (size_t)r * Kpad;
  const short* b1 = Yt + (size_t)(r + 16) * Kpad;
  int k8 = g * 8;
  for (int s = s_lo; s < s_hi; ++s) {
    int k = s * 32 + k8;
    s16x8 a = {0,0,0,0,0,0,0,0};
    if (k < K) {                       // only the final step of a segment masks
      f32x4 a0 = *(const f32x4*)(gp + k);
      f32x4 a1 = *(const f32x4*)(gp + k + 4);
      a[0]=f2bf(a0.x); a[1]=f2bf(a0.y); a[2]=f2bf(a0.z); a[3]=f2bf(a0.w);
      a[4]=f2bf(a1.x); a[5]=f2bf(a1.y); a[6]=f2bf(a1.z); a[7]=f2bf(a1.w);
    }
    s16x8 vb0 = *(const s16x8*)(b0 + k);   // pad region is zeroed
    s16x8 vb1 = *(const s16x8*)(b1 + k);
    acc0 = __builtin_amdgcn_mfma_f32_16x16x32_bf16(a, vb0, acc0, 0, 0, 0);
    acc1 = __builtin_amdgcn_mfma_f32_16x16x32_bf16(a, vb1, acc1, 0, 0, 0);
  }
}

__global__ __launch_bounds__(256) void gemm_skinny(
    const float* __restrict__ Gv2v, const float* __restrict__ Gv2e,
    const float* __restrict__ Ge2e, const float* __restrict__ Ge2f,
    const float* __restrict__ Gf2f, const short* __restrict__ Yt,
    float* __restrict__ out)
{
  int bid  = blockIdx.x;
  int lane = threadIdx.x & 63, w = threadIdx.x >> 6;

  const float *G0, *G1; const short *Y0, *Y1;
  int K0, Kp0, K1, Kp1, st0, st1, tile; size_t ob;
  if (bid < 500) {           // zf = Ge2f@Ye2f + Gf2f@Yf2f   (625 steps, heaviest first)
    tile = bid;
    G0 = Ge2f; Y0 = Yt + 769024;  K0 = 12000; Kp0 = 12000; st0 = 375;
    G1 = Gf2f; Y1 = Yt + 1153024; K1 = 8000;  Kp1 = 8000;  st1 = 250;
    ob = (size_t)18000 * 32;
  } else if (bid < 1250) {   // ze = Gv2e@Yv2e + Ge2e@Ye2e   (563 steps)
    tile = bid - 500;
    G0 = Gv2e; Y0 = Yt + 192512;  K0 = 6000;  Kp0 = 6016;  st0 = 188;
    G1 = Ge2e; Y1 = Yt + 385024;  K1 = 12000; Kp1 = 12000; st1 = 375;
    ob = (size_t)6000 * 32;
  } else {                   // zv = Gv2v@Yv2v               (188 steps)
    tile = bid - 1250;
    G0 = Gv2v; Y0 = Yt;           K0 = 6000;  Kp0 = 6016;  st0 = 188;
    G1 = nullptr; Y1 = nullptr;   K1 = 0; Kp1 = 0; st1 = 0;
    ob = 0;
  }
  int total = st0 + st1;
  int row0  = tile * 16;
  int s_lo  = (total * w) >> 2;
  int s_hi  = (total * (w + 1)) >> 2;

  f32x4 acc0 = {0.f,0.f,0.f,0.f}, acc1 = {0.f,0.f,0.f,0.f};
  int e0 = s_hi < st0 ? s_hi : st0;
  run_seg(G0, Y0, K0, Kp0, row0, s_lo, e0, lane, acc0, acc1);
  if (st1 > 0 && s_hi > st0) {
    int l1 = s_lo > st0 ? s_lo - st0 : 0;
    run_seg(G1, Y1, K1, Kp1, row0, l1, s_hi - st0, lane, acc0, acc1);
  }

  // cross-wave reduce: C/D layout (verified): col = lane&15, row = (lane>>4)*4+reg
  __shared__ float red[4][512];
  int r = lane & 15, g = lane >> 4;
  #pragma unroll
  for (int q = 0; q < 4; ++q) {
    int rw = g * 4 + q;
    red[w][rw * 32 + r]      = acc0[q];
    red[w][rw * 32 + 16 + r] = acc1[q];
  }
  __syncthreads();
  #pragma unroll
  for (int i = 0; i < 2; ++i) {
    int e = (int)threadIdx.x + i * 256;
    float s = red[0][e] + red[1][e] + red[2][e] + red[3][e];
    out[ob + (size_t)row0 * 32 + e] = s;
  }
}

extern "C" void kernel_launch(void* const* d_in, const int* in_sizes, int n_in,
                              void* d_out, int out_size, void* d_ws, size_t ws_size,
                              hipStream_t stream) {
  const float* xv   = (const float*)d_in[0];
  const float* xe   = (const float*)d_in[1];
  const float* xf   = (const float*)d_in[2];
  const float* Gv2v = (const float*)d_in[3];
  const float* Gv2e = (const float*)d_in[4];
  const float* Ge2e = (const float*)d_in[5];
  const float* Ge2f = (const float*)d_in[6];
  const float* Gf2f = (const float*)d_in[7];
  const float* Wv2v = (const float*)d_in[8];
  const float* Wv2e = (const float*)d_in[9];
  const float* We2e = (const float*)d_in[10];
  const float* We2f = (const float*)d_in[11];
  const float* Wf2f = (const float*)d_in[12];
  short* Yt  = (short*)d_ws;
  float* out = (float*)d_out;

  hipLaunchKernelGGL(build_yt, dim3(174), dim3(256), 0, stream,
                     xv, xe, xf, Wv2v, Wv2e, We2e, We2f, Wf2f, Yt);
  hipLaunchKernelGGL(gemm_skinny, dim3(1625), dim3(256), 0, stream,
                     Gv2v, Gv2e, Ge2e, Ge2f, Gf2f, Yt, out);
}